// Round 1
// baseline (1160.303 us; speedup 1.0000x reference)
//
#include <hip/hip_runtime.h>
#include <math.h>

// Problem constants
#define B_SZ   4
#define SEQ    8192
#define H_DIM  512
#define P_DIM  256
#define M_ROWS (B_SZ * SEQ)   // 32768
#define ND     512            // packed N = 2*P (re || im)
#define KD     512            // K = H
#define CH     128            // scan chunk length
#define NC     (SEQ / CH)     // 64 chunks

// Workspace layout (in floats)
#define OFF_BMAT  0u                         // [2][512][512]
#define OFF_CMAT  524288u                    // [2][512][512]
#define OFF_ABAR  1048576u                   // [2][256][2]
#define OFF_APOW  1049600u                   // [2][256][2]
#define OFF_COEF  1050624u                   // [2][256][2]
#define OFF_CARRY 1051648u                   // [B][NC][P][2]
#define OFF_INIT  1182720u                   // [B][NC][P][2]
#define OFF_SBUF  1313792u                   // [B][SEQ][512] (one dir at a time)
// total = 18,091,008 floats = 72.4 MB

// ---------------------------------------------------------------------------
// Per-p parameter derivation: a_bar = exp(lam*dt), coef = (a_bar-1)/lam,
// apow = a_bar^CH
__global__ void param_kernel(const float* __restrict__ Lre,
                             const float* __restrict__ Lim,
                             const float* __restrict__ ldt,
                             float* __restrict__ abar,
                             float* __restrict__ apow,
                             float* __restrict__ coef) {
    int d = blockIdx.x, p = threadIdx.x;
    int ip = d * P_DIM + p;
    float lr = Lre[ip], li = Lim[ip];
    float dt = expf(ldt[ip]);
    float e   = expf(lr * dt);
    float ang = li * dt;
    float ar = e * cosf(ang), ai = e * sinf(ang);
    // coef = (a-1)/lam = (a-1)*conj(lam)/|lam|^2
    float nr = ar - 1.0f, ni = ai;
    float den = lr * lr + li * li;
    float cr = (nr * lr + ni * li) / den;
    float ci = (ni * lr - nr * li) / den;
    int o = d * 512 + 2 * p;
    abar[o] = ar;  abar[o + 1] = ai;
    float eC = expf(lr * dt * (float)CH);
    float aC = ang * (float)CH;
    apow[o] = eC * cosf(aC);  apow[o + 1] = eC * sinf(aC);
    coef[o] = cr;  coef[o + 1] = ci;
}

// Bmat[d][p][h]     = Re(coef*(Bre+iBim)),  Bmat[d][256+p][h] = Im(...)
__global__ void bmat_kernel(const float* __restrict__ Bre,
                            const float* __restrict__ Bim,
                            const float* __restrict__ coef,
                            float* __restrict__ Bmat) {
    int idx = blockIdx.x * 256 + threadIdx.x;   // over 2*256*512
    int h = idx & 511;
    int p = (idx >> 9) & 255;
    int d = idx >> 17;
    float cr = coef[d * 512 + 2 * p], ci = coef[d * 512 + 2 * p + 1];
    float br = Bre[idx], bi = Bim[idx];         // [d][p][h] flat == idx
    Bmat[(d * 512 + p) * 512 + h]       = cr * br - ci * bi;
    Bmat[(d * 512 + 256 + p) * 512 + h] = cr * bi + ci * br;
}

// Cmat[d][h][p] = C_re[d][h][p],  Cmat[d][h][256+p] = -C_im[d][h][p]
__global__ void cmat_kernel(const float* __restrict__ Cre,
                            const float* __restrict__ Cim,
                            float* __restrict__ Cmat) {
    int idx = blockIdx.x * 256 + threadIdx.x;   // over 2*512*256
    int p = idx & 255;
    int h = (idx >> 8) & 511;
    int d = idx >> 17;
    Cmat[(d * 512 + h) * 512 + p]       = Cre[idx];
    Cmat[(d * 512 + h) * 512 + 256 + p] = -Cim[idx];
}

// ---------------------------------------------------------------------------
// C[M][512] = A[M][512] * Bm[512][512]^T (Bm rows = output cols, contig in K)
// EPI 0: C = acc           (GEMM1 -> bu)
// EPI 1: C = acc + x*(D0+D1)  (GEMM2 dir0)
// EPI 2: C += acc             (GEMM2 dir1)
template<int EPI>
__global__ __launch_bounds__(256)
void gemm_nt(const float* __restrict__ A, const float* __restrict__ Bm,
             float* __restrict__ C, const float* __restrict__ X,
             const float* __restrict__ Dv) {
    __shared__ float As[16][64];
    __shared__ float Bs[16][64];
    const int t  = threadIdx.x;
    const int tx = t & 15, ty = t >> 4;
    const int m0 = blockIdx.y * 64;
    const int n0 = blockIdx.x * 64;
    const int lr = t >> 2;            // 0..63 tile row
    const int lc = (t & 3) << 2;      // 0,4,8,12 k offset
    float acc[4][4] = {{0.f}};
    const float* Ap = &A[(m0 + lr) * 512 + lc];
    const float* Bp = &Bm[(n0 + lr) * 512 + lc];
    for (int kt = 0; kt < 512; kt += 16) {
        float4 av = *(const float4*)(Ap + kt);
        float4 bv = *(const float4*)(Bp + kt);
        __syncthreads();
        As[lc + 0][lr] = av.x; As[lc + 1][lr] = av.y;
        As[lc + 2][lr] = av.z; As[lc + 3][lr] = av.w;
        Bs[lc + 0][lr] = bv.x; Bs[lc + 1][lr] = bv.y;
        Bs[lc + 2][lr] = bv.z; Bs[lc + 3][lr] = bv.w;
        __syncthreads();
#pragma unroll
        for (int kk = 0; kk < 16; ++kk) {
            float4 a4 = *(const float4*)&As[kk][ty << 2];
            float4 b4 = *(const float4*)&Bs[kk][tx << 2];
            float ar[4] = {a4.x, a4.y, a4.z, a4.w};
            float br[4] = {b4.x, b4.y, b4.z, b4.w};
#pragma unroll
            for (int i = 0; i < 4; ++i)
#pragma unroll
                for (int j = 0; j < 4; ++j)
                    acc[i][j] = fmaf(ar[i], br[j], acc[i][j]);
        }
    }
#pragma unroll
    for (int i = 0; i < 4; ++i) {
        int row = m0 + (ty << 2) + i;
        int col = n0 + (tx << 2);
        float4 out;
        if (EPI == 0) {
            out.x = acc[i][0]; out.y = acc[i][1];
            out.z = acc[i][2]; out.w = acc[i][3];
        } else if (EPI == 1) {
            float4 xv = *(const float4*)&X[row * 512 + col];
            out.x = acc[i][0] + xv.x * (Dv[col + 0] + Dv[512 + col + 0]);
            out.y = acc[i][1] + xv.y * (Dv[col + 1] + Dv[512 + col + 1]);
            out.z = acc[i][2] + xv.z * (Dv[col + 2] + Dv[512 + col + 2]);
            out.w = acc[i][3] + xv.w * (Dv[col + 3] + Dv[512 + col + 3]);
        } else {
            float4 cv = *(const float4*)&C[row * 512 + col];
            out.x = cv.x + acc[i][0]; out.y = cv.y + acc[i][1];
            out.z = cv.z + acc[i][2]; out.w = cv.w + acc[i][3];
        }
        *(float4*)&C[row * 512 + col] = out;
    }
}

// ---------------------------------------------------------------------------
// Scan pass A: per-chunk local carry (state starting from 0 over the chunk)
template<int DIR>
__global__ __launch_bounds__(256)
void scan_carry(const float* __restrict__ S, const float* __restrict__ abar,
                float* __restrict__ carry) {
    int b = blockIdx.x, c = blockIdx.y, p = threadIdx.x;
    float ar = abar[2 * p], ai = abar[2 * p + 1];
    float sr = 0.f, si = 0.f;
    long base = ((long)b * SEQ + (long)c * CH) * 512;
    for (int ii = 0; ii < CH; ++ii) {
        int i = (DIR == 0) ? ii : (CH - 1 - ii);
        const float* r = S + base + (long)i * 512;
        float re = r[p], im = r[256 + p];
        float nr = fmaf(ar, sr, fmaf(-ai, si, re));
        float ni = fmaf(ar, si, fmaf(ai, sr, im));
        sr = nr; si = ni;
    }
    int o = (b * NC + c) * 512 + 2 * p;
    carry[o] = sr; carry[o + 1] = si;
}

// Scan pass B: serial combine across chunks (per b,p): init = prefix state
template<int DIR>
__global__ void scan_comb(const float* __restrict__ carry,
                          float* __restrict__ init,
                          const float* __restrict__ apow) {
    int b = blockIdx.x, p = threadIdx.x;
    float pr = apow[2 * p], pi = apow[2 * p + 1];
    float sr = 0.f, si = 0.f;
    for (int cc = 0; cc < NC; ++cc) {
        int c = (DIR == 0) ? cc : (NC - 1 - cc);
        int o = (b * NC + c) * 512 + 2 * p;
        init[o] = sr; init[o + 1] = si;
        float cr = carry[o], ci = carry[o + 1];
        float nr = fmaf(pr, sr, fmaf(-pi, si, cr));
        float ni = fmaf(pr, si, fmaf(pi, sr, ci));
        sr = nr; si = ni;
    }
}

// Scan pass C: re-scan chunk from correct init, write states in place
template<int DIR>
__global__ __launch_bounds__(256)
void scan_final(float* __restrict__ S, const float* __restrict__ abar,
                const float* __restrict__ init) {
    int b = blockIdx.x, c = blockIdx.y, p = threadIdx.x;
    float ar = abar[2 * p], ai = abar[2 * p + 1];
    int o = (b * NC + c) * 512 + 2 * p;
    float sr = init[o], si = init[o + 1];
    long base = ((long)b * SEQ + (long)c * CH) * 512;
    for (int ii = 0; ii < CH; ++ii) {
        int i = (DIR == 0) ? ii : (CH - 1 - ii);
        float* r = S + base + (long)i * 512;
        float re = r[p], im = r[256 + p];
        float nr = fmaf(ar, sr, fmaf(-ai, si, re));
        float ni = fmaf(ar, si, fmaf(ai, sr, im));
        sr = nr; si = ni;
        r[p] = sr; r[256 + p] = si;
    }
}

// ---------------------------------------------------------------------------
extern "C" void kernel_launch(void* const* d_in, const int* in_sizes, int n_in,
                              void* d_out, int out_size, void* d_ws, size_t ws_size,
                              hipStream_t stream) {
    const float* x   = (const float*)d_in[0];
    const float* Lre = (const float*)d_in[1];
    const float* Lim = (const float*)d_in[2];
    const float* ldt = (const float*)d_in[3];
    const float* Bre = (const float*)d_in[4];
    const float* Bim = (const float*)d_in[5];
    const float* Cre = (const float*)d_in[6];
    const float* Cim = (const float*)d_in[7];
    const float* Dv  = (const float*)d_in[8];
    float* y  = (float*)d_out;
    float* ws = (float*)d_ws;

    float* Bmat  = ws + OFF_BMAT;
    float* Cmat  = ws + OFF_CMAT;
    float* abar  = ws + OFF_ABAR;
    float* apow  = ws + OFF_APOW;
    float* coef  = ws + OFF_COEF;
    float* carry = ws + OFF_CARRY;
    float* initb = ws + OFF_INIT;
    float* Sbuf  = ws + OFF_SBUF;

    param_kernel<<<2, 256, 0, stream>>>(Lre, Lim, ldt, abar, apow, coef);
    bmat_kernel<<<1024, 256, 0, stream>>>(Bre, Bim, coef, Bmat);
    cmat_kernel<<<1024, 256, 0, stream>>>(Cre, Cim, Cmat);

    dim3 gg(ND / 64, M_ROWS / 64);   // (8, 512)
    dim3 gs(B_SZ, NC);               // (4, 64)

    // direction 0 (forward)
    gemm_nt<0><<<gg, 256, 0, stream>>>(x, Bmat, Sbuf, nullptr, nullptr);
    scan_carry<0><<<gs, 256, 0, stream>>>(Sbuf, abar, carry);
    scan_comb<0><<<B_SZ, 256, 0, stream>>>(carry, initb, apow);
    scan_final<0><<<gs, 256, 0, stream>>>(Sbuf, abar, initb);
    gemm_nt<1><<<gg, 256, 0, stream>>>(Sbuf, Cmat, y, x, Dv);

    // direction 1 (backward scan on original indices; no data reversal)
    gemm_nt<0><<<gg, 256, 0, stream>>>(x, Bmat + 262144, Sbuf, nullptr, nullptr);
    scan_carry<1><<<gs, 256, 0, stream>>>(Sbuf, abar + 512, carry);
    scan_comb<1><<<B_SZ, 256, 0, stream>>>(carry, initb, apow + 512);
    scan_final<1><<<gs, 256, 0, stream>>>(Sbuf, abar + 512, initb);
    gemm_nt<2><<<gg, 256, 0, stream>>>(Sbuf, Cmat + 262144, y, nullptr, nullptr);
}

// Round 2
// 328.927 us; speedup vs baseline: 3.5275x; 3.5275x over previous
//
#include <hip/hip_runtime.h>
#include <math.h>

typedef unsigned short ushort_t;
typedef __bf16 bf16x8 __attribute__((ext_vector_type(8)));
typedef ushort_t ushort8v __attribute__((ext_vector_type(8)));
typedef float f32x4 __attribute__((ext_vector_type(4)));

#define B_SZ   4
#define SEQ    8192
#define M_ROWS (B_SZ * SEQ)   // 32768
#define CH     128
#define NC     (SEQ / CH)     // 64

// fp32 -> bf16 round-to-nearest-even
__device__ __forceinline__ ushort_t f2bf(float f) {
    unsigned u = __float_as_uint(f);
    u = u + 0x7fffu + ((u >> 16) & 1u);
    return (ushort_t)(u >> 16);
}
__device__ __forceinline__ float bf2f(ushort_t b) {
    return __uint_as_float(((unsigned)b) << 16);
}

__device__ __forceinline__ void load16_lds(const void* g, void* l) {
    __builtin_amdgcn_global_load_lds(
        (const __attribute__((address_space(1))) unsigned int*)g,
        (__attribute__((address_space(3))) unsigned int*)l, 16, 0, 0);
}

// ---------------------------------------------------------------------------
__global__ void param_kernel(const float* __restrict__ Lre,
                             const float* __restrict__ Lim,
                             const float* __restrict__ ldt,
                             float* __restrict__ abar,
                             float* __restrict__ apow,
                             float* __restrict__ coef) {
    int d = blockIdx.x, p = threadIdx.x;
    int ip = d * 256 + p;
    float lr = Lre[ip], li = Lim[ip];
    float dt = expf(ldt[ip]);
    float e   = expf(lr * dt);
    float ang = li * dt;
    float ar = e * cosf(ang), ai = e * sinf(ang);
    float nr = ar - 1.0f, ni = ai;
    float den = lr * lr + li * li;
    float cr = (nr * lr + ni * li) / den;
    float ci = (ni * lr - nr * li) / den;
    int o = d * 512 + 2 * p;
    abar[o] = ar;  abar[o + 1] = ai;
    float eC = expf(lr * dt * (float)CH);
    float aC = ang * (float)CH;
    apow[o] = eC * cosf(aC);  apow[o + 1] = eC * sinf(aC);
    coef[o] = cr;  coef[o + 1] = ci;
}

__global__ void bmat_kernel(const float* __restrict__ Bre,
                            const float* __restrict__ Bim,
                            const float* __restrict__ coef,
                            ushort_t* __restrict__ Bmat) {
    int idx = blockIdx.x * 256 + threadIdx.x;   // 2*256*512
    int h = idx & 511;
    int p = (idx >> 9) & 255;
    int d = idx >> 17;
    float cr = coef[d * 512 + 2 * p], ci = coef[d * 512 + 2 * p + 1];
    float br = Bre[idx], bi = Bim[idx];
    Bmat[(d * 512 + p) * 512 + h]       = f2bf(cr * br - ci * bi);
    Bmat[(d * 512 + 256 + p) * 512 + h] = f2bf(cr * bi + ci * br);
}

__global__ void cmat_kernel(const float* __restrict__ Cre,
                            const float* __restrict__ Cim,
                            ushort_t* __restrict__ Cmat) {
    int idx = blockIdx.x * 256 + threadIdx.x;   // 2*512*256
    int p = idx & 255;
    int h = (idx >> 8) & 511;
    int d = idx >> 17;
    Cmat[(d * 512 + h) * 512 + p]       = f2bf(Cre[idx]);
    Cmat[(d * 512 + h) * 512 + 256 + p] = f2bf(-Cim[idx]);
}

__global__ void conv_x_kernel(const float* __restrict__ x,
                              ushort_t* __restrict__ X16) {
    int i = blockIdx.x * 256 + threadIdx.x;   // one per 4 elements
    float4 v = ((const float4*)x)[i];
    ushort_t o[4] = {f2bf(v.x), f2bf(v.y), f2bf(v.z), f2bf(v.w)};
    *(uint2*)&X16[(size_t)i * 4] = *(const uint2*)o;
}

// ---------------------------------------------------------------------------
// bf16 MFMA GEMM: C[M][512] = A16[M][512] * Bm16[512][512]^T
// EPI 0: BU16 = bf16(acc)
// EPI 1: Cf = acc + x*(D0+D1)
// EPI 2: Cf += acc
template<int EPI>
__global__ __launch_bounds__(256)
void gemm_mfma(const ushort_t* __restrict__ A, const ushort_t* __restrict__ Bm,
               ushort_t* __restrict__ Cb, float* __restrict__ Cf,
               const float* __restrict__ X, const float* __restrict__ Dv) {
    __shared__ ushort_t As[128 * 32];
    __shared__ ushort_t Bs[128 * 32];
    const int tid  = threadIdx.x;
    const int lane = tid & 63;
    const int wv   = tid >> 6;          // 0..3
    const int wrow = wv >> 1, wcol = wv & 1;
    const int l15  = lane & 15, lq = lane >> 4;
    const int m0 = blockIdx.y * 128;
    const int n0 = blockIdx.x * 128;

    f32x4 acc[4][4];
#pragma unroll
    for (int i = 0; i < 4; ++i)
#pragma unroll
        for (int j = 0; j < 4; ++j)
            acc[i][j] = (f32x4){0.f, 0.f, 0.f, 0.f};

    // staging geometry: instr j (0,1), wave wv -> 16 rows starting r0
    const int grow_l = lane >> 2;       // 0..15 within group
    const int gk8    = (lane & 3) * 8;  // bf16 element offset within 32-K tile

    const ushort_t* aF = As + (wrow * 64 + l15) * 32 + lq * 8;
    const ushort_t* bF = Bs + (wcol * 64 + l15) * 32 + lq * 8;

    for (int kt = 0; kt < 512; kt += 32) {
        __syncthreads();
#pragma unroll
        for (int j = 0; j < 2; ++j) {
            const int r0 = j * 64 + wv * 16;
            load16_lds(&A[(size_t)(m0 + r0 + grow_l) * 512 + kt + gk8],
                       (void*)&As[r0 * 32]);
            load16_lds(&Bm[(size_t)(n0 + r0 + grow_l) * 512 + kt + gk8],
                       (void*)&Bs[r0 * 32]);
        }
        __syncthreads();

        bf16x8 af[4], bf[4];
#pragma unroll
        for (int mi = 0; mi < 4; ++mi) {
            union { ushort8v u; bf16x8 b; } cv;
            cv.u = *(const ushort8v*)(aF + mi * 512);
            af[mi] = cv.b;
        }
#pragma unroll
        for (int ni = 0; ni < 4; ++ni) {
            union { ushort8v u; bf16x8 b; } cv;
            cv.u = *(const ushort8v*)(bF + ni * 512);
            bf[ni] = cv.b;
        }
#pragma unroll
        for (int mi = 0; mi < 4; ++mi)
#pragma unroll
            for (int ni = 0; ni < 4; ++ni)
                acc[mi][ni] = __builtin_amdgcn_mfma_f32_16x16x32_bf16(
                    af[mi], bf[ni], acc[mi][ni], 0, 0, 0);
    }

    // epilogue: C/D layout col=lane&15, row=lq*4+reg
#pragma unroll
    for (int mi = 0; mi < 4; ++mi) {
#pragma unroll
        for (int ni = 0; ni < 4; ++ni) {
            const int col = n0 + wcol * 64 + ni * 16 + l15;
            float dsum = 0.f;
            if (EPI == 1) dsum = Dv[col] + Dv[512 + col];
#pragma unroll
            for (int r = 0; r < 4; ++r) {
                const int row = m0 + wrow * 64 + mi * 16 + lq * 4 + r;
                const size_t idx = (size_t)row * 512 + col;
                float v = acc[mi][ni][r];
                if (EPI == 0) {
                    Cb[idx] = f2bf(v);
                } else if (EPI == 1) {
                    Cf[idx] = v + X[idx] * dsum;
                } else {
                    Cf[idx] += v;
                }
            }
        }
    }
}

// ---------------------------------------------------------------------------
template<int DIR>
__global__ __launch_bounds__(256)
void scan_carry(const ushort_t* __restrict__ S, const float* __restrict__ abar,
                float* __restrict__ carry) {
    int b = blockIdx.x, c = blockIdx.y, p = threadIdx.x;
    float ar = abar[2 * p], ai = abar[2 * p + 1];
    float sr = 0.f, si = 0.f;
    size_t base = ((size_t)b * SEQ + (size_t)c * CH) * 512;
    for (int ii = 0; ii < CH; ++ii) {
        int i = (DIR == 0) ? ii : (CH - 1 - ii);
        const ushort_t* r = S + base + (size_t)i * 512;
        float re = bf2f(r[p]), im = bf2f(r[256 + p]);
        float nr = fmaf(ar, sr, fmaf(-ai, si, re));
        float ni = fmaf(ar, si, fmaf(ai, sr, im));
        sr = nr; si = ni;
    }
    int o = (b * NC + c) * 512 + 2 * p;
    carry[o] = sr; carry[o + 1] = si;
}

template<int DIR>
__global__ void scan_comb(const float* __restrict__ carry,
                          float* __restrict__ init,
                          const float* __restrict__ apow) {
    int b = blockIdx.x, p = threadIdx.x;
    float pr = apow[2 * p], pi = apow[2 * p + 1];
    float sr = 0.f, si = 0.f;
    for (int cc = 0; cc < NC; ++cc) {
        int c = (DIR == 0) ? cc : (NC - 1 - cc);
        int o = (b * NC + c) * 512 + 2 * p;
        init[o] = sr; init[o + 1] = si;
        float cr = carry[o], ci = carry[o + 1];
        float nr = fmaf(pr, sr, fmaf(-pi, si, cr));
        float ni = fmaf(pr, si, fmaf(pi, sr, ci));
        sr = nr; si = ni;
    }
}

template<int DIR>
__global__ __launch_bounds__(256)
void scan_final(ushort_t* __restrict__ S, const float* __restrict__ abar,
                const float* __restrict__ init) {
    int b = blockIdx.x, c = blockIdx.y, p = threadIdx.x;
    float ar = abar[2 * p], ai = abar[2 * p + 1];
    int o = (b * NC + c) * 512 + 2 * p;
    float sr = init[o], si = init[o + 1];
    size_t base = ((size_t)b * SEQ + (size_t)c * CH) * 512;
    for (int ii = 0; ii < CH; ++ii) {
        int i = (DIR == 0) ? ii : (CH - 1 - ii);
        ushort_t* r = S + base + (size_t)i * 512;
        float re = bf2f(r[p]), im = bf2f(r[256 + p]);
        float nr = fmaf(ar, sr, fmaf(-ai, si, re));
        float ni = fmaf(ar, si, fmaf(ai, sr, im));
        sr = nr; si = ni;
        r[p] = f2bf(sr); r[256 + p] = f2bf(si);
    }
}

// ---------------------------------------------------------------------------
// ws layout (bytes):
//  X16   : 0                (33,554,432)
//  SB16  : 33,554,432       (33,554,432)
//  Bmat16: 67,108,864       (1,048,576)
//  Cmat16: 68,157,440       (1,048,576)
//  abar  : 69,206,016       (4 KB)
//  apow  : 69,210,112       (4 KB)
//  coef  : 69,214,208       (4 KB)
//  carry : 69,218,304       (512 KB)
//  init  : 69,742,592       (512 KB)
extern "C" void kernel_launch(void* const* d_in, const int* in_sizes, int n_in,
                              void* d_out, int out_size, void* d_ws, size_t ws_size,
                              hipStream_t stream) {
    const float* x   = (const float*)d_in[0];
    const float* Lre = (const float*)d_in[1];
    const float* Lim = (const float*)d_in[2];
    const float* ldt = (const float*)d_in[3];
    const float* Bre = (const float*)d_in[4];
    const float* Bim = (const float*)d_in[5];
    const float* Cre = (const float*)d_in[6];
    const float* Cim = (const float*)d_in[7];
    const float* Dv  = (const float*)d_in[8];
    float* y = (float*)d_out;
    char* ws = (char*)d_ws;

    ushort_t* X16  = (ushort_t*)(ws);
    ushort_t* SB16 = (ushort_t*)(ws + 33554432);
    ushort_t* Bm16 = (ushort_t*)(ws + 67108864);
    ushort_t* Cm16 = (ushort_t*)(ws + 68157440);
    float* abar  = (float*)(ws + 69206016);
    float* apow  = (float*)(ws + 69210112);
    float* coef  = (float*)(ws + 69214208);
    float* carry = (float*)(ws + 69218304);
    float* initb = (float*)(ws + 69742592);

    param_kernel<<<2, 256, 0, stream>>>(Lre, Lim, ldt, abar, apow, coef);
    bmat_kernel<<<1024, 256, 0, stream>>>(Bre, Bim, coef, Bm16);
    cmat_kernel<<<1024, 256, 0, stream>>>(Cre, Cim, Cm16);
    conv_x_kernel<<<16384, 256, 0, stream>>>(x, X16);

    dim3 gg(4, 256);            // N/128, M/128
    dim3 gs(B_SZ, NC);

    // direction 0 (forward)
    gemm_mfma<0><<<gg, 256, 0, stream>>>(X16, Bm16, SB16, nullptr, nullptr, nullptr);
    scan_carry<0><<<gs, 256, 0, stream>>>(SB16, abar, carry);
    scan_comb<0><<<B_SZ, 256, 0, stream>>>(carry, initb, apow);
    scan_final<0><<<gs, 256, 0, stream>>>(SB16, abar, initb);
    gemm_mfma<1><<<gg, 256, 0, stream>>>(SB16, Cm16, nullptr, y, x, Dv);

    // direction 1 (backward on original indices)
    gemm_mfma<0><<<gg, 256, 0, stream>>>(X16, Bm16 + 262144, SB16, nullptr, nullptr, nullptr);
    scan_carry<1><<<gs, 256, 0, stream>>>(SB16, abar + 512, carry);
    scan_comb<1><<<B_SZ, 256, 0, stream>>>(carry, initb, apow + 512);
    scan_final<1><<<gs, 256, 0, stream>>>(SB16, abar + 512, initb);
    gemm_mfma<2><<<gg, 256, 0, stream>>>(SB16, Cm16 + 262144, nullptr, y, nullptr, nullptr);
}

// Round 3
// 286.932 us; speedup vs baseline: 4.0438x; 1.1464x over previous
//
#include <hip/hip_runtime.h>
#include <math.h>

typedef unsigned short ushort_t;
typedef __bf16 bf16x8 __attribute__((ext_vector_type(8)));
typedef ushort_t ushort8v __attribute__((ext_vector_type(8)));
typedef float f32x4 __attribute__((ext_vector_type(4)));

#define B_SZ   4
#define SEQ    8192
#define M_ROWS (B_SZ * SEQ)   // 32768
#define CH     128
#define NC     (SEQ / CH)     // 64

__device__ __forceinline__ ushort_t f2bf(float f) {
    unsigned u = __float_as_uint(f);
    u = u + 0x7fffu + ((u >> 16) & 1u);
    return (ushort_t)(u >> 16);
}
__device__ __forceinline__ float bf2f(ushort_t b) {
    return __uint_as_float(((unsigned)b) << 16);
}

__device__ __forceinline__ void load16_lds(const void* g, void* l) {
    __builtin_amdgcn_global_load_lds(
        (const __attribute__((address_space(1))) unsigned int*)g,
        (__attribute__((address_space(3))) unsigned int*)l, 16, 0, 0);
}

// ---------------------------------------------------------------------------
// Fused prep: per-idx computes one Bmat complex pair (interleaved rows) and
// one Cmat complex pair; h==0 threads also write abar/apow.
// Layouts: Bmat[k][h], k = d*512 + 2p(+1)  (re,im interleaved), 512 h each.
//          Cmat[h][k], k = d*512 + 2p(+1), 1024 k per h row.
__global__ void prep_kernel(const float* __restrict__ Lre,
                            const float* __restrict__ Lim,
                            const float* __restrict__ ldt,
                            const float* __restrict__ Bre,
                            const float* __restrict__ Bim,
                            const float* __restrict__ Cre,
                            const float* __restrict__ Cim,
                            float* __restrict__ abar,
                            float* __restrict__ apow,
                            ushort_t* __restrict__ Bmat,
                            ushort_t* __restrict__ Cmat) {
    int idx = blockIdx.x * 256 + threadIdx.x;   // 0 .. 262143
    // ---- B side: idx -> [d][p][h]
    int h = idx & 511;
    int p = (idx >> 9) & 255;
    int d = idx >> 17;
    int ip = d * 256 + p;
    float lr = Lre[ip], li = Lim[ip];
    float dt = expf(ldt[ip]);
    float e   = expf(lr * dt);
    float ang = li * dt;
    float ar = e * cosf(ang), ai = e * sinf(ang);
    float nr = ar - 1.0f, ni = ai;
    float den = lr * lr + li * li;
    float cr = (nr * lr + ni * li) / den;
    float ci = (ni * lr - nr * li) / den;
    float br = Bre[idx], bi = Bim[idx];
    Bmat[(d * 512 + 2 * p) * 512 + h]     = f2bf(cr * br - ci * bi);
    Bmat[(d * 512 + 2 * p + 1) * 512 + h] = f2bf(cr * bi + ci * br);
    if (h == 0) {
        int o = d * 512 + 2 * p;
        abar[o] = ar;  abar[o + 1] = ai;
        float eC = expf(lr * dt * (float)CH);
        float aC = ang * (float)CH;
        apow[o] = eC * cosf(aC);  apow[o + 1] = eC * sinf(aC);
    }
    // ---- C side: idx -> [d][h][p]
    int p2 = idx & 255;
    int h2 = (idx >> 8) & 511;
    int d2 = idx >> 17;
    Cmat[h2 * 1024 + d2 * 512 + 2 * p2]     = f2bf(Cre[idx]);
    Cmat[h2 * 1024 + d2 * 512 + 2 * p2 + 1] = f2bf(-Cim[idx]);
}

__global__ void conv_x_kernel(const float* __restrict__ x,
                              ushort_t* __restrict__ X16) {
    int i = blockIdx.x * 256 + threadIdx.x;
    float4 v = ((const float4*)x)[i];
    ushort_t o[4] = {f2bf(v.x), f2bf(v.y), f2bf(v.z), f2bf(v.w)};
    *(uint2*)&X16[(size_t)i * 4] = *(const uint2*)o;
}

// ---------------------------------------------------------------------------
// bf16 MFMA GEMM, NT output tiles of 128 (N = NT*128), K = KD_.
// XCD-swizzled 1D grid of 256*NT blocks: all NT n-tiles of an m-tile are
// adjacent on one XCD -> A tile fetched into exactly one L2.
// EPI 0: Cb[row*(NT*128)+col] = bf16(acc)
// EPI 1: Cf[row*512+col] = acc + X[row*512+col]*(Dv[col]+Dv[512+col])
template<int EPI, int KD_, int NT>
__global__ __launch_bounds__(256)
void gemm_mfma(const ushort_t* __restrict__ A, const ushort_t* __restrict__ Bm,
               ushort_t* __restrict__ Cb, float* __restrict__ Cf,
               const float* __restrict__ X, const float* __restrict__ Dv) {
    __shared__ ushort_t As[128 * 32];
    __shared__ ushort_t Bs[128 * 32];
    const int tid  = threadIdx.x;
    const int lane = tid & 63;
    const int wv   = tid >> 6;
    const int wrow = wv >> 1, wcol = wv & 1;
    const int l15  = lane & 15, lq = lane >> 4;

    const int lin = blockIdx.x;
    const int xcd = lin & 7;
    const int j   = lin >> 3;
    const int mt  = xcd * 32 + j / NT;
    const int nt  = j % NT;
    const int m0 = mt * 128;
    const int n0 = nt * 128;
    const int CN = NT * 128;

    f32x4 acc[4][4];
#pragma unroll
    for (int i = 0; i < 4; ++i)
#pragma unroll
        for (int jj = 0; jj < 4; ++jj)
            acc[i][jj] = (f32x4){0.f, 0.f, 0.f, 0.f};

    const int grow_l = lane >> 2;
    const int gk8    = (lane & 3) * 8;

    const ushort_t* aF = As + (wrow * 64 + l15) * 32 + lq * 8;
    const ushort_t* bF = Bs + (wcol * 64 + l15) * 32 + lq * 8;

    for (int kt = 0; kt < KD_; kt += 32) {
        __syncthreads();
#pragma unroll
        for (int j2 = 0; j2 < 2; ++j2) {
            const int r0 = j2 * 64 + wv * 16;
            load16_lds(&A[(size_t)(m0 + r0 + grow_l) * KD_ + kt + gk8],
                       (void*)&As[r0 * 32]);
            load16_lds(&Bm[(size_t)(n0 + r0 + grow_l) * KD_ + kt + gk8],
                       (void*)&Bs[r0 * 32]);
        }
        __syncthreads();

        bf16x8 af[4], bfr[4];
#pragma unroll
        for (int mi = 0; mi < 4; ++mi) {
            union { ushort8v u; bf16x8 b; } cv;
            cv.u = *(const ushort8v*)(aF + mi * 512);
            af[mi] = cv.b;
        }
#pragma unroll
        for (int ni = 0; ni < 4; ++ni) {
            union { ushort8v u; bf16x8 b; } cv;
            cv.u = *(const ushort8v*)(bF + ni * 512);
            bfr[ni] = cv.b;
        }
#pragma unroll
        for (int mi = 0; mi < 4; ++mi)
#pragma unroll
            for (int ni = 0; ni < 4; ++ni)
                acc[mi][ni] = __builtin_amdgcn_mfma_f32_16x16x32_bf16(
                    af[mi], bfr[ni], acc[mi][ni], 0, 0, 0);
    }

#pragma unroll
    for (int mi = 0; mi < 4; ++mi) {
#pragma unroll
        for (int ni = 0; ni < 4; ++ni) {
            const int col = n0 + wcol * 64 + ni * 16 + l15;
            float dsum = 0.f;
            if (EPI == 1) dsum = Dv[col] + Dv[512 + col];
#pragma unroll
            for (int r = 0; r < 4; ++r) {
                const int row = m0 + wrow * 64 + mi * 16 + lq * 4 + r;
                if (EPI == 0) {
                    Cb[(size_t)row * CN + col] = f2bf(acc[mi][ni][r]);
                } else {
                    const size_t idx = (size_t)row * 512 + col;
                    Cf[idx] = acc[mi][ni][r] + X[idx] * dsum;
                }
            }
        }
    }
}

// ---------------------------------------------------------------------------
// Scans over SB[row][1024], k = dir*512 + 2p(+1). Both dirs per launch:
// threads 0..255 dir0 (forward), 256..511 dir1 (backward).
__global__ __launch_bounds__(512)
void scan_carry(const ushort_t* __restrict__ S, const float* __restrict__ abar,
                float* __restrict__ carry) {
    int b = blockIdx.x, c = blockIdx.y, t = threadIdx.x;
    int dir = t >> 8, p = t & 255;
    float ar = abar[dir * 512 + 2 * p], ai = abar[dir * 512 + 2 * p + 1];
    float sr = 0.f, si = 0.f;
    const ushort_t* base = S + ((size_t)b * SEQ + (size_t)c * CH) * 1024
                             + dir * 512 + 2 * p;
    for (int ii = 0; ii < CH; ++ii) {
        int i = dir ? (CH - 1 - ii) : ii;
        unsigned u = *(const unsigned*)(base + (size_t)i * 1024);
        float re = bf2f((ushort_t)(u & 0xffffu));
        float im = bf2f((ushort_t)(u >> 16));
        float nr = fmaf(ar, sr, fmaf(-ai, si, re));
        float ni = fmaf(ar, si, fmaf(ai, sr, im));
        sr = nr; si = ni;
    }
    int o = (b * NC + c) * 1024 + dir * 512 + 2 * p;
    carry[o] = sr; carry[o + 1] = si;
}

__global__ __launch_bounds__(512)
void scan_comb(const float* __restrict__ carry, float* __restrict__ init,
               const float* __restrict__ apow) {
    int b = blockIdx.x, t = threadIdx.x;
    int dir = t >> 8, p = t & 255;
    float pr = apow[dir * 512 + 2 * p], pi = apow[dir * 512 + 2 * p + 1];
    float sr = 0.f, si = 0.f;
    for (int cc = 0; cc < NC; ++cc) {
        int c = dir ? (NC - 1 - cc) : cc;
        int o = (b * NC + c) * 1024 + dir * 512 + 2 * p;
        init[o] = sr; init[o + 1] = si;
        float cr = carry[o], ci = carry[o + 1];
        float nr = fmaf(pr, sr, fmaf(-pi, si, cr));
        float ni = fmaf(pr, si, fmaf(pi, sr, ci));
        sr = nr; si = ni;
    }
}

__global__ __launch_bounds__(512)
void scan_final(ushort_t* __restrict__ S, const float* __restrict__ abar,
                const float* __restrict__ init) {
    int b = blockIdx.x, c = blockIdx.y, t = threadIdx.x;
    int dir = t >> 8, p = t & 255;
    float ar = abar[dir * 512 + 2 * p], ai = abar[dir * 512 + 2 * p + 1];
    int o = (b * NC + c) * 1024 + dir * 512 + 2 * p;
    float sr = init[o], si = init[o + 1];
    ushort_t* base = S + ((size_t)b * SEQ + (size_t)c * CH) * 1024
                       + dir * 512 + 2 * p;
    for (int ii = 0; ii < CH; ++ii) {
        int i = dir ? (CH - 1 - ii) : ii;
        unsigned* addr = (unsigned*)(base + (size_t)i * 1024);
        unsigned u = *addr;
        float re = bf2f((ushort_t)(u & 0xffffu));
        float im = bf2f((ushort_t)(u >> 16));
        float nr = fmaf(ar, sr, fmaf(-ai, si, re));
        float ni = fmaf(ar, si, fmaf(ai, sr, im));
        sr = nr; si = ni;
        *addr = ((unsigned)f2bf(si) << 16) | (unsigned)f2bf(sr);
    }
}

// ---------------------------------------------------------------------------
// ws layout (bytes):
//  SB16 : 0           (67,108,864)  [M][1024] bf16 states both dirs
//  X16  : 67,108,864  (33,554,432)  bf16 x   (carry/init alias its head
//                                    after GEMM1 is done with X16)
//  Bm16 : 100,663,296 (1,048,576)
//  Cm16 : 101,711,872 (1,048,576)
//  abar : 102,760,448 (4,096)
//  apow : 102,764,544 (4,096)
//  carry: 67,108,864  (1,048,576)   alias
//  init : 68,157,440  (1,048,576)   alias
extern "C" void kernel_launch(void* const* d_in, const int* in_sizes, int n_in,
                              void* d_out, int out_size, void* d_ws, size_t ws_size,
                              hipStream_t stream) {
    const float* x   = (const float*)d_in[0];
    const float* Lre = (const float*)d_in[1];
    const float* Lim = (const float*)d_in[2];
    const float* ldt = (const float*)d_in[3];
    const float* Bre = (const float*)d_in[4];
    const float* Bim = (const float*)d_in[5];
    const float* Cre = (const float*)d_in[6];
    const float* Cim = (const float*)d_in[7];
    const float* Dv  = (const float*)d_in[8];
    float* y = (float*)d_out;
    char* ws = (char*)d_ws;

    ushort_t* SB16 = (ushort_t*)(ws);
    ushort_t* X16  = (ushort_t*)(ws + 67108864);
    ushort_t* Bm16 = (ushort_t*)(ws + 100663296);
    ushort_t* Cm16 = (ushort_t*)(ws + 101711872);
    float* abar  = (float*)(ws + 102760448);
    float* apow  = (float*)(ws + 102764544);
    float* carry = (float*)(ws + 67108864);   // alias over X16 (dead region)
    float* initb = (float*)(ws + 68157440);

    prep_kernel<<<1024, 256, 0, stream>>>(Lre, Lim, ldt, Bre, Bim, Cre, Cim,
                                          abar, apow, Bm16, Cm16);
    conv_x_kernel<<<16384, 256, 0, stream>>>(x, X16);

    // GEMM1: SB[M][1024] = X16[M][512] * Bm16[1024][512]^T
    gemm_mfma<0, 512, 8><<<2048, 256, 0, stream>>>(X16, Bm16, SB16, nullptr,
                                                   nullptr, nullptr);

    dim3 gs(B_SZ, NC);
    scan_carry<<<gs, 512, 0, stream>>>(SB16, abar, carry);
    scan_comb<<<B_SZ, 512, 0, stream>>>(carry, initb, apow);
    scan_final<<<gs, 512, 0, stream>>>(SB16, abar, initb);

    // GEMM2: y[M][512] = SB16[M][1024] * Cm16[512][1024]^T + x*(D0+D1)
    gemm_mfma<1, 1024, 4><<<1024, 256, 0, stream>>>(SB16, Cm16, nullptr, y,
                                                    x, Dv);
}